// Round 7
// baseline (153.850 us; speedup 1.0000x reference)
//
#include <hip/hip_runtime.h>
#include <math.h>

#define H 512
#define W 512
#define IMG (H*W)
#define NIMG 32           // 16 images from y_hat + 16 from y

typedef unsigned long long u64;

__device__ __forceinline__ int reflect_idx(int i, int n) {
    // jnp.pad mode="reflect": -1 -> 1, -2 -> 2, n -> n-2, n+1 -> n-3
    if (i < 0) i = -i;
    if (i >= n) i = 2 * n - 2 - i;
    return i;
}

// Composed 7-tap kernels: blur(g, 5-tap) composed with sobel [1,2,1]/[-1,0,1].
// Symmetric  (g * [1,2,1]):  [S0,S1,S2,S3,S2,S1,S0]
// Antisym    (g * [-1,0,1]): [-A1,-A2,-A3,0,A3,A2,A1]
#define S0 0.05448868454964294f
#define S1 0.35317871110251920f
#define S2 0.94551131545035710f
#define S3 1.29364257779496160f
#define A1 0.05448868454964294f
#define A2 0.24420134200323332f
#define A3 0.34813126234460456f

// ---------------------------------------------------------------------------
// Kernel 1: gray -> (separable 7x7) gx,gy -> mag^2+dir -> NMS -> thresholds ->
// strong/weak bitplanes. Tile 64x48, block (64,8)=512 thr, 50.1 KB LDS ->
// 3 blocks/CU = 24/32 waves (75%). Halo ratio 58/48 = 1.21.
// LDS: sg[58][80] f32 (gray, cols x0-8..x0+67), hxy[58][68] float2;
//      sm[52][68] f32 + sbin[52][68] u8 alias sg (gray dead after h-pass).
// Bitplane layout: plane[img][word][row] (coalesced for k_hyst).
// ---------------------------------------------------------------------------
#define TY 48
#define SGROWS 58   // TY + 10
#define SMROWS 52   // ceil((TY+2)/4)*4

__global__ __launch_bounds__(512) void k_edges(const float* __restrict__ yhat,
                                               const float* __restrict__ yy,
                                               u64* __restrict__ strongP,
                                               u64* __restrict__ weakP) {
    __shared__ __align__(16) char lds[18560 + 31552];
    float (*sg)[80] = (float (*)[80])lds;                          // 58 x 80 f32
    float (*hxy)[68][2] = (float (*)[68][2])(lds + 18560);         // 58 x 68 f32x2
    float (*sm)[68] = (float (*)[68])lds;                          // 52 x 68 f32 (alias)
    unsigned char (*sbin)[68] = (unsigned char (*)[68])(lds + 14144); // 52 x 68 u8

    const int n = blockIdx.z;
    const float* src = (n < 16) ? (yhat + (size_t)n * 3 * IMG)
                                : (yy + (size_t)(n - 16) * 3 * IMG);
    const int x0 = blockIdx.x * 64;
    const int y0 = blockIdx.y * TY;
    const int tx = threadIdx.x, ty = threadIdx.y;
    const int tid = ty * 64 + tx;

    // ---- stage gray: rows y0-4 .. y0+53 (58), cols x0-8 .. x0+67 (76) ----
    // hybrid: float4 fast path where fully in-image; per-component reflect else
    const int xb = x0 - 8;
    for (int t = tid; t < SGROWS * 19; t += 512) {
        int sy = t / 19, f = t % 19;
        int iy = reflect_idx(y0 - 4 + sy, H);
        const float* row = src + (size_t)iy * W;
        int c0 = xb + 4 * f;
        float4 gr;
        if (c0 >= 0 && c0 + 3 < W) {
            const float4* rp = (const float4*)(row + c0);
            float4 r = rp[0];
            float4 g = rp[IMG / 4];
            float4 b = rp[2 * (IMG / 4)];
            gr.x = 0.299f * r.x + 0.587f * g.x + 0.114f * b.x;
            gr.y = 0.299f * r.y + 0.587f * g.y + 0.114f * b.y;
            gr.z = 0.299f * r.z + 0.587f * g.z + 0.114f * b.z;
            gr.w = 0.299f * r.w + 0.587f * g.w + 0.114f * b.w;
        } else {
            float v[4];
#pragma unroll
            for (int j = 0; j < 4; j++) {
                int ix = reflect_idx(c0 + j, W);
                v[j] = 0.299f * row[ix] + 0.587f * row[IMG + ix]
                     + 0.114f * row[2 * IMG + ix];
            }
            gr.x = v[0]; gr.y = v[1]; gr.z = v[2]; gr.w = v[3];
        }
        *(float4*)&sg[sy][4 * f] = gr;
    }
    __syncthreads();

    // ---- h-pass: 58 rows x 17 groups of 4 cols; out col sx = image x0-1+sx,
    //      needs sg cols sx+4 .. sx+10 -> float4s g+1 .. g+3 ----
    for (int t = tid; t < SGROWS * 17; t += 512) {
        int sy = t / 17, g = t % 17;
        const float4* p = (const float4*)&sg[sy][0];
        float4 q0 = p[g + 1], q1 = p[g + 2], q2 = p[g + 3];
        float w[12] = {q0.x, q0.y, q0.z, q0.w, q1.x, q1.y, q1.z, q1.w,
                       q2.x, q2.y, q2.z, q2.w};
#pragma unroll
        for (int j = 0; j < 4; j++) {
            float hx = A3 * (w[j + 4] - w[j + 2]) + A2 * (w[j + 5] - w[j + 1])
                     + A1 * (w[j + 6] - w[j + 0]);
            float hy = S3 * w[j + 3] + S2 * (w[j + 4] + w[j + 2])
                     + S1 * (w[j + 5] + w[j + 1]) + S0 * (w[j + 6] + w[j + 0]);
            *(float2*)&hxy[sy][4 * g + j][0] = make_float2(hx, hy);
        }
    }
    __syncthreads();

    // ---- v-pass: mag^2 rows 0..51 (image y0-1+my), cols 0..65 (image x0-1+c) ----
    for (int t = tid; t < 13 * 66; t += 512) {
        int rg = t / 66, c = t % 66;
        float hx[10], hy[10];
#pragma unroll
        for (int i = 0; i < 10; i++) {
            float2 v = *(const float2*)&hxy[4 * rg + i][c][0];
            hx[i] = v.x; hy[i] = v.y;
        }
        int imgcol = x0 - 1 + c;
        bool colok = (unsigned)imgcol < (unsigned)W;
#pragma unroll
        for (int j = 0; j < 4; j++) {
            int my = 4 * rg + j;
            float gx = S3 * hx[j + 3] + S2 * (hx[j + 4] + hx[j + 2])
                     + S1 * (hx[j + 5] + hx[j + 1]) + S0 * (hx[j + 6] + hx[j + 0]);
            float gy = A3 * (hy[j + 4] - hy[j + 2]) + A2 * (hy[j + 5] - hy[j + 1])
                     + A1 * (hy[j + 6] - hy[j + 0]);
            int imgrow = y0 - 1 + my;
            bool ok = colok && ((unsigned)imgrow < (unsigned)H);
            float m2 = ok ? (gx * gx + gy * gy + 1e-12f) : 0.f;   // mag^2
            sm[my][c] = m2;
            float ax = fabsf(gx), ay = fabsf(gy);
            int d;
            if (ay <= 0.4142135623730951f * ax) d = 1;          // 0 deg
            else if (ay >= 2.414213562373095f * ax) d = 68;     // 90 deg
            else d = ((gx > 0.f) == (gy > 0.f)) ? 69 : 67;      // 45 / 135
            sbin[my][c] = (unsigned char)d;
        }
    }
    __syncthreads();

    // ---- NMS + double threshold + ballot; plane[img][word][row] ----
#pragma unroll
    for (int k = 0; k < 6; k++) {
        int ry = ty + 8 * k;   // 0..47; wave = one ty row -> ballot across tx
        const float* cp = &sm[ry + 1][tx + 1];
        float mag = cp[0];
        int d = sbin[ry + 1][tx + 1];
        float n1 = cp[d];
        float n2 = cp[-d];
        float nms = (mag >= n1 && mag >= n2) ? mag : 0.f;
        u64 strong = __ballot(nms >= 0.04f);   // (0.2)^2
        u64 weak = __ballot(nms >= 0.01f);     // (0.1)^2
        if (tx == 0 && (y0 + ry) < H) {
            size_t off = ((size_t)n * 8 + blockIdx.x) * H + (y0 + ry);
            strongP[off] = strong;
            weakP[off] = weak;
        }
    }
}

// ---------------------------------------------------------------------------
// Kernel 2: bit-parallel hysteresis (10 iters, exact via light cone) + diff
// count. One wave per 32x32 tile per image-pair; lane l holds row ty0-10+l
// (52 active lanes) as a 64-bit window covering x0-10 .. x0+53.
// Plane layout [img][word][row] -> lane-consecutive loads (coalesced).
// ---------------------------------------------------------------------------
__device__ __forceinline__ u64 ldw(const u64* p, int img, int y, int w, bool ok) {
    return (ok && w >= 0 && w < 8) ? p[((size_t)img * 8 + w) * H + y] : 0ULL;
}

__global__ __launch_bounds__(256) void k_hyst(const u64* __restrict__ strongP,
                                              const u64* __restrict__ weakP,
                                              unsigned int* __restrict__ partials) {
    __shared__ unsigned int part[4];
    const int wy = threadIdx.x >> 6;
    const int wave = blockIdx.x * 4 + wy;
    const int lane = threadIdx.x & 63;
    const int tile = wave & 255;
    const int pair = wave >> 8;          // 0..15
    const int tx0 = (tile & 15) * 32;
    const int ty0 = (tile >> 4) * 32;

    const int y = ty0 - 10 + lane;
    const bool rowok = (lane < 52) && (y >= 0) && (y < H);
    const int yc = rowok ? y : 0;        // clamped address, result masked below
    const int s = tx0 - 10;
    const int w0i = s >> 6;              // arithmetic shift: -10>>6 = -1
    const int r = s & 63;                // in {22,54}, never 0

    const int imgA = pair, imgB = pair + 16;
    u64 sA, wA, sB, wB;
    {
        u64 lo, hi;
        lo = ldw(strongP, imgA, yc, w0i, rowok); hi = ldw(strongP, imgA, yc, w0i + 1, rowok);
        sA = (lo >> r) | (hi << (64 - r));
        lo = ldw(weakP, imgA, yc, w0i, rowok);   hi = ldw(weakP, imgA, yc, w0i + 1, rowok);
        wA = (lo >> r) | (hi << (64 - r));
        lo = ldw(strongP, imgB, yc, w0i, rowok); hi = ldw(strongP, imgB, yc, w0i + 1, rowok);
        sB = (lo >> r) | (hi << (64 - r));
        lo = ldw(weakP, imgB, yc, w0i, rowok);   hi = ldw(weakP, imgB, yc, w0i + 1, rowok);
        wB = (lo >> r) | (hi << (64 - r));
    }

#pragma unroll
    for (int it = 0; it < 10; it++) {
        u64 up = __shfl_up(sA, 1), dn = __shfl_down(sA, 1);
        u64 t = up | sA | dn;
        sA |= (t | (t << 1) | (t >> 1)) & wA;
        up = __shfl_up(sB, 1); dn = __shfl_down(sB, 1);
        t = up | sB | dn;
        sB |= (t | (t << 1) | (t >> 1)) & wB;
    }

    // central 32x32: lanes 10..41, bits 10..41
    unsigned int c = 0;
    if (lane >= 10 && lane < 42) {
        const u64 mask = ((1ULL << 42) - (1ULL << 10));
        c = (unsigned int)__popcll((sA ^ sB) & mask);
    }
#pragma unroll
    for (int off = 32; off > 0; off >>= 1) c += __shfl_down(c, off);
    if (lane == 0) part[wy] = c;
    __syncthreads();
    if (threadIdx.x == 0)
        partials[blockIdx.x] = part[0] + part[1] + part[2] + part[3];
}

// ---------------------------------------------------------------------------
// Kernel 3: sum 1024 partials, scale, write scalar. One block.
// ---------------------------------------------------------------------------
__global__ __launch_bounds__(256) void k_final(const unsigned int* __restrict__ partials,
                                               float* __restrict__ out) {
    __shared__ unsigned int part[4];
    unsigned int c = 0;
    for (int i = threadIdx.x; i < 1024; i += 256) c += partials[i];
#pragma unroll
    for (int off = 32; off > 0; off >>= 1) c += __shfl_down(c, off);
    const int lane = threadIdx.x & 63;
    const int wy = threadIdx.x >> 6;
    if (lane == 0) part[wy] = c;
    __syncthreads();
    if (threadIdx.x == 0)
        out[0] = (float)(part[0] + part[1] + part[2] + part[3]) * (1.0f / 4194304.0f);
}

extern "C" void kernel_launch(void* const* d_in, const int* in_sizes, int n_in,
                              void* d_out, int out_size, void* d_ws, size_t ws_size,
                              hipStream_t stream) {
    const float* yhat = (const float*)d_in[0];
    const float* yy = (const float*)d_in[1];

    u64* strongP = (u64*)d_ws;                   // 32*8*512 u64 = 1 MB
    u64* weakP = strongP + (size_t)NIMG * H * 8; // 1 MB
    unsigned int* partials = (unsigned int*)(weakP + (size_t)NIMG * H * 8); // 4 KB

    dim3 eblk(64, 8);
    dim3 egrd(W / 64, (H + TY - 1) / TY, NIMG);  // 8 x 11 x 32
    k_edges<<<egrd, eblk, 0, stream>>>(yhat, yy, strongP, weakP);

    // 256 tiles x 16 pairs = 4096 waves, 4 waves/block
    k_hyst<<<1024, 256, 0, stream>>>(strongP, weakP, partials);
    k_final<<<1, 256, 0, stream>>>(partials, (float*)d_out);
}

// Round 8
// 146.641 us; speedup vs baseline: 1.0492x; 1.0492x over previous
//
#include <hip/hip_runtime.h>
#include <math.h>

#define H 512
#define W 512
#define IMG (H*W)
#define NIMG 32           // 16 images from y_hat + 16 from y
#define NSTRIP 10         // 56-col output strips per row
#define SW 56
#define RB 32             // rows per band
#define NBAND 16

typedef unsigned long long u64;

__device__ __forceinline__ int reflect_idx(int i, int n) {
    if (i < 0) i = -i;
    if (i >= n) i = 2 * n - 2 - i;
    return i;
}

__device__ __forceinline__ float bperm_f(int addr, float v) {
    return __int_as_float(__builtin_amdgcn_ds_bpermute(addr, __float_as_int(v)));
}

// Composed 7-tap kernels: blur(5-tap gaussian) composed with sobel [1,2,1]/[-1,0,1].
#define S0 0.05448868454964294f
#define S1 0.35317871110251920f
#define S2 0.94551131545035710f
#define S3 1.29364257779496160f
#define A1 0.05448868454964294f
#define A2 0.24420134200323332f
#define A3 0.34813126234460456f

// ---------------------------------------------------------------------------
// Kernel 1 (line-scan, no LDS, no barriers): one wave per (image, strip, band).
// Lane = gray col 56s-4+lane. March down 40 gray rows; h via 6 bpermutes +
// 7-deep register FIFO; v-taps from FIFO; NMS from 3-deep mag FIFO (+L/R).
// Output: 56-bit words, plane[img][strip][row].
// ---------------------------------------------------------------------------
__global__ __launch_bounds__(256) void k_edges(const float* __restrict__ yhat,
                                               const float* __restrict__ yy,
                                               u64* __restrict__ strongP,
                                               u64* __restrict__ weakP) {
    const int wid = blockIdx.x * 4 + (threadIdx.x >> 6);
    const int lane = threadIdx.x & 63;
    const int n = wid / (NSTRIP * NBAND);
    const int rem = wid - n * (NSTRIP * NBAND);
    const int s = rem >> 4;          // strip 0..9
    const int band = rem & 15;       // 0..15
    const int y0 = band * RB;
    const float* src = (n < 16) ? (yhat + (size_t)n * 3 * IMG)
                                : (yy + (size_t)(n - 16) * 3 * IMG);

    const int c = s * SW - 4 + lane;             // this lane's gray column
    const int cx = reflect_idx(c, W);            // reflected address (x halo)
    const bool colok = ((unsigned)c < (unsigned)W);
    const u64 omask = (s == 9) ? 0xFFull : 0x00FFFFFFFFFFFFFFull;

    // bpermute byte-addresses (wrap mod 64 in HW; wrapped lanes unused)
    const int aM3 = ((lane - 3) << 2), aM2 = ((lane - 2) << 2), aM1 = ((lane - 1) << 2);
    const int aP1 = ((lane + 1) << 2), aP2 = ((lane + 2) << 2), aP3 = ((lane + 3) << 2);

    float hx[7], hy[7];
    float mPrev = 0.f, mPrevL = 0.f, mPrevR = 0.f;
    float mCur = 0.f, mCurL = 0.f, mCurR = 0.f;
    int dCur = 0, dNew = 0;

    u64 outBase = ((size_t)n * NSTRIP + s) * H;

    for (int i = 0; i < RB + 8; i++) {
        // ---- shift h FIFO, compute new h row ----
#pragma unroll
        for (int j = 0; j < 6; j++) { hx[j] = hx[j + 1]; hy[j] = hy[j + 1]; }
        {
            int gr = reflect_idx(y0 - 4 + i, H);
            const float* p = src + (size_t)gr * W + cx;
            float g = 0.299f * p[0] + 0.587f * p[IMG] + 0.114f * p[2 * IMG];
            float gm1 = bperm_f(aM1, g), gp1 = bperm_f(aP1, g);
            float gm2 = bperm_f(aM2, g), gp2 = bperm_f(aP2, g);
            float gm3 = bperm_f(aM3, g), gp3 = bperm_f(aP3, g);
            hx[6] = A3 * (gp1 - gm1) + A2 * (gp2 - gm2) + A1 * (gp3 - gm3);
            hy[6] = S3 * g + S2 * (gp1 + gm1) + S1 * (gp2 + gm2) + S0 * (gp3 + gm3);
        }

        float mNew = 0.f, mNewL = 0.f, mNewR = 0.f;
        if (i >= 6) {
            // ---- mag row mr = y0-7+i (center of h FIFO = hx[3]) ----
            float gx = S3 * hx[3] + S2 * (hx[4] + hx[2])
                     + S1 * (hx[5] + hx[1]) + S0 * (hx[6] + hx[0]);
            float gy = A3 * (hy[4] - hy[2]) + A2 * (hy[5] - hy[1])
                     + A1 * (hy[6] - hy[0]);
            int mr = y0 - 7 + i;
            bool ok = colok && ((unsigned)mr < (unsigned)H);
            mNew = ok ? (gx * gx + gy * gy + 1e-12f) : 0.f;    // mag^2
            mNewL = bperm_f(aM1, mNew);
            mNewR = bperm_f(aP1, mNew);
            float ax = fabsf(gx), ay = fabsf(gy);
            dNew = (ay <= 0.4142135623730951f * ax) ? 0
                 : (ay >= 2.414213562373095f * ax) ? 2
                 : (((gx > 0.f) == (gy > 0.f)) ? 1 : 3);
        }

        if (i >= 8) {
            // ---- NMS + thresholds at row t = y0-8+i ----
            float n1 = (dCur == 0) ? mCurR : (dCur == 1) ? mNewR
                     : (dCur == 2) ? mNew : mNewL;
            float n2 = (dCur == 0) ? mCurL : (dCur == 1) ? mPrevL
                     : (dCur == 2) ? mPrev : mPrevR;
            bool okn = (mCur >= n1) && (mCur >= n2);
            u64 bs = __ballot(okn && (mCur >= 0.04f));   // (0.2)^2
            u64 bw = __ballot(okn && (mCur >= 0.01f));   // (0.1)^2
            if (lane == 0) {
                int t = y0 - 8 + i;
                strongP[outBase + t] = (bs >> 4) & omask;
                weakP[outBase + t] = (bw >> 4) & omask;
            }
        }

        if (i >= 6) {
            mPrev = mCur; mPrevL = mCurL; mPrevR = mCurR;
            mCur = mNew; mCurL = mNewL; mCurR = mNewR;
            dCur = dNew;
        }
    }
}

// ---------------------------------------------------------------------------
// Kernel 2: bit-parallel hysteresis (10 iters, exact via light cone) + diff
// count. One wave per 32x32 tile per image-pair; lane l = row ty0-10+l.
// Loads from 56-bit strip words via 3-word funnel shift.
// ---------------------------------------------------------------------------
__device__ __forceinline__ u64 ldw10(const u64* p, int img, int y, int q, bool ok) {
    return (ok && q >= 0 && q < NSTRIP) ? p[((size_t)img * NSTRIP + q) * H + y] : 0ULL;
}

__global__ __launch_bounds__(256) void k_hyst(const u64* __restrict__ strongP,
                                              const u64* __restrict__ weakP,
                                              unsigned int* __restrict__ partials) {
    __shared__ unsigned int part[4];
    const int wy = threadIdx.x >> 6;
    const int wave = blockIdx.x * 4 + wy;
    const int lane = threadIdx.x & 63;
    const int tile = wave & 255;
    const int pair = wave >> 8;          // 0..15
    const int tx0 = (tile & 15) * 32;
    const int ty0 = (tile >> 4) * 32;

    const int y = ty0 - 10 + lane;
    const bool rowok = (lane < 52) && (y >= 0) && (y < H);
    const int yc = rowok ? y : 0;

    // window covers cols x .. x+63; 56-bit words
    const int x = tx0 - 10;
    const int q0 = (x < 0) ? -1 : (x / 56);
    const int r = x - 56 * q0;           // 1..55, never 0 for our x values
    const int sh1 = 56 - r;
    const bool need3 = (r > 48);
    const int sh2 = 112 - r;             // < 64 iff need3

    const int imgA = pair, imgB = pair + 16;
    u64 sA, wA, sB, wB;
    {
        u64 w0, w1, w2;
        w0 = ldw10(strongP, imgA, yc, q0, rowok);
        w1 = ldw10(strongP, imgA, yc, q0 + 1, rowok);
        w2 = need3 ? ldw10(strongP, imgA, yc, q0 + 2, rowok) : 0ULL;
        sA = (w0 >> r) | (w1 << sh1) | (need3 ? (w2 << sh2) : 0ULL);
        w0 = ldw10(weakP, imgA, yc, q0, rowok);
        w1 = ldw10(weakP, imgA, yc, q0 + 1, rowok);
        w2 = need3 ? ldw10(weakP, imgA, yc, q0 + 2, rowok) : 0ULL;
        wA = (w0 >> r) | (w1 << sh1) | (need3 ? (w2 << sh2) : 0ULL);
        w0 = ldw10(strongP, imgB, yc, q0, rowok);
        w1 = ldw10(strongP, imgB, yc, q0 + 1, rowok);
        w2 = need3 ? ldw10(strongP, imgB, yc, q0 + 2, rowok) : 0ULL;
        sB = (w0 >> r) | (w1 << sh1) | (need3 ? (w2 << sh2) : 0ULL);
        w0 = ldw10(weakP, imgB, yc, q0, rowok);
        w1 = ldw10(weakP, imgB, yc, q0 + 1, rowok);
        w2 = need3 ? ldw10(weakP, imgB, yc, q0 + 2, rowok) : 0ULL;
        wB = (w0 >> r) | (w1 << sh1) | (need3 ? (w2 << sh2) : 0ULL);
    }

#pragma unroll
    for (int it = 0; it < 10; it++) {
        u64 up = __shfl_up(sA, 1), dn = __shfl_down(sA, 1);
        u64 t = up | sA | dn;
        sA |= (t | (t << 1) | (t >> 1)) & wA;
        up = __shfl_up(sB, 1); dn = __shfl_down(sB, 1);
        t = up | sB | dn;
        sB |= (t | (t << 1) | (t >> 1)) & wB;
    }

    // central 32x32: lanes 10..41, bits 10..41
    unsigned int cgt = 0;
    if (lane >= 10 && lane < 42) {
        const u64 mask = ((1ULL << 42) - (1ULL << 10));
        cgt = (unsigned int)__popcll((sA ^ sB) & mask);
    }
#pragma unroll
    for (int off = 32; off > 0; off >>= 1) cgt += __shfl_down(cgt, off);
    if (lane == 0) part[wy] = cgt;
    __syncthreads();
    if (threadIdx.x == 0)
        partials[blockIdx.x] = part[0] + part[1] + part[2] + part[3];
}

// ---------------------------------------------------------------------------
// Kernel 3: sum 1024 partials, scale, write scalar. One block.
// ---------------------------------------------------------------------------
__global__ __launch_bounds__(256) void k_final(const unsigned int* __restrict__ partials,
                                               float* __restrict__ out) {
    __shared__ unsigned int part[4];
    unsigned int c = 0;
    for (int i = threadIdx.x; i < 1024; i += 256) c += partials[i];
#pragma unroll
    for (int off = 32; off > 0; off >>= 1) c += __shfl_down(c, off);
    const int lane = threadIdx.x & 63;
    const int wy = threadIdx.x >> 6;
    if (lane == 0) part[wy] = c;
    __syncthreads();
    if (threadIdx.x == 0)
        out[0] = (float)(part[0] + part[1] + part[2] + part[3]) * (1.0f / 4194304.0f);
}

extern "C" void kernel_launch(void* const* d_in, const int* in_sizes, int n_in,
                              void* d_out, int out_size, void* d_ws, size_t ws_size,
                              hipStream_t stream) {
    const float* yhat = (const float*)d_in[0];
    const float* yy = (const float*)d_in[1];

    u64* strongP = (u64*)d_ws;                        // 32*10*512 u64 = 1.31 MB
    u64* weakP = strongP + (size_t)NIMG * NSTRIP * H; // 1.31 MB
    unsigned int* partials = (unsigned int*)(weakP + (size_t)NIMG * NSTRIP * H);

    // 32 img x 10 strips x 16 bands = 5120 waves, 4 waves/block
    k_edges<<<1280, 256, 0, stream>>>(yhat, yy, strongP, weakP);

    // 256 tiles x 16 pairs = 4096 waves, 4 waves/block
    k_hyst<<<1024, 256, 0, stream>>>(strongP, weakP, partials);
    k_final<<<1, 256, 0, stream>>>(partials, (float*)d_out);
}

// Round 9
// 142.622 us; speedup vs baseline: 1.0787x; 1.0282x over previous
//
#include <hip/hip_runtime.h>
#include <math.h>

#define H 512
#define W 512
#define IMG (H*W)
#define NIMG 32           // 16 images from y_hat + 16 from y
#define NSTRIP 10         // 56-col output strips per row
#define SW 56
#define RB 26             // output rows per band
#define NBAND 20          // 20*26 = 520 >= 512 (tail band guarded)

typedef unsigned long long u64;

__device__ __forceinline__ int reflect_idx(int i, int n) {
    if (i < 0) i = -i;
    if (i >= n) i = 2 * n - 2 - i;
    return i;
}

__device__ __forceinline__ float bperm_f(int addr, float v) {
    return __int_as_float(__builtin_amdgcn_ds_bpermute(addr, __float_as_int(v)));
}

// Composed 7-tap kernels: blur(5-tap gaussian) composed with sobel [1,2,1]/[-1,0,1].
#define S0 0.05448868454964294f
#define S1 0.35317871110251920f
#define S2 0.94551131545035710f
#define S3 1.29364257779496160f
#define A1 0.05448868454964294f
#define A2 0.24420134200323332f
#define A3 0.34813126234460456f

// ---------------------------------------------------------------------------
// Kernel 1 (line-scan, no LDS/barriers, software-pipelined, fully unrolled):
// one wave per (image, strip, band). Lane = gray col 56s-4+lane. Prefetch next
// row's r,g,b while computing current; 7-deep h FIFO (SSA after unroll);
// NMS from 3-deep mag FIFO (+L/R via 2 bpermutes).
// Output: 56-bit words, plane[img][strip][row].
// ---------------------------------------------------------------------------
__global__ __launch_bounds__(256) void k_edges(const float* __restrict__ yhat,
                                               const float* __restrict__ yy,
                                               u64* __restrict__ strongP,
                                               u64* __restrict__ weakP) {
    const int wid = blockIdx.x * 4 + (threadIdx.x >> 6);
    const int lane = threadIdx.x & 63;
    const int n = wid / (NSTRIP * NBAND);
    const int rem = wid - n * (NSTRIP * NBAND);
    const int s = rem / NBAND;
    const int band = rem - s * NBAND;
    const int y0 = band * RB;
    const float* src = (n < 16) ? (yhat + (size_t)n * 3 * IMG)
                                : (yy + (size_t)(n - 16) * 3 * IMG);

    const int c = s * SW - 4 + lane;             // this lane's gray column
    const int cx = reflect_idx(c, W);            // reflected address (x halo)
    const bool colok = ((unsigned)c < (unsigned)W);
    const u64 omask = (s == 9) ? 0xFFull : 0x00FFFFFFFFFFFFFFull;

    const int aM3 = ((lane - 3) << 2), aM2 = ((lane - 2) << 2), aM1 = ((lane - 1) << 2);
    const int aP1 = ((lane + 1) << 2), aP2 = ((lane + 2) << 2), aP3 = ((lane + 3) << 2);

    float hx[7], hy[7];
#pragma unroll
    for (int j = 0; j < 7; j++) { hx[j] = 0.f; hy[j] = 0.f; }
    float mPrev = 0.f, mPrevL = 0.f, mPrevR = 0.f;
    float mCur = 0.f, mCurL = 0.f, mCurR = 0.f;
    int dCur = 0;

    const u64 outBase = ((size_t)n * NSTRIP + s) * H;

    // prefetch gray row y0-4
    float rN, gN, bN;
    {
        int gr = reflect_idx(y0 - 4, H);
        const float* p = src + (size_t)gr * W + cx;
        rN = p[0]; gN = p[IMG]; bN = p[2 * IMG];
    }

    // ---- prime: i = 0..7 (fill FIFO; mag rows for i=6,7) ----
#pragma unroll
    for (int i = 0; i < 8; i++) {
        float g = 0.299f * rN + 0.587f * gN + 0.114f * bN;
        {   // prefetch next row
            int gr = reflect_idx(y0 - 3 + i, H);
            const float* p = src + (size_t)gr * W + cx;
            rN = p[0]; gN = p[IMG]; bN = p[2 * IMG];
        }
        float gm1 = bperm_f(aM1, g), gp1 = bperm_f(aP1, g);
        float gm2 = bperm_f(aM2, g), gp2 = bperm_f(aP2, g);
        float gm3 = bperm_f(aM3, g), gp3 = bperm_f(aP3, g);
#pragma unroll
        for (int j = 0; j < 6; j++) { hx[j] = hx[j + 1]; hy[j] = hy[j + 1]; }
        hx[6] = A3 * (gp1 - gm1) + A2 * (gp2 - gm2) + A1 * (gp3 - gm3);
        hy[6] = S3 * g + S2 * (gp1 + gm1) + S1 * (gp2 + gm2) + S0 * (gp3 + gm3);

        if (i >= 6) {   // compile-time after unroll
            float gx = S3 * hx[3] + S2 * (hx[4] + hx[2])
                     + S1 * (hx[5] + hx[1]) + S0 * (hx[6] + hx[0]);
            float gy = A3 * (hy[4] - hy[2]) + A2 * (hy[5] - hy[1])
                     + A1 * (hy[6] - hy[0]);
            int mr = y0 - 7 + i;
            bool ok = colok && ((unsigned)mr < (unsigned)H);
            float mNew = ok ? (gx * gx + gy * gy + 1e-12f) : 0.f;  // mag^2
            float mNewL = bperm_f(aM1, mNew);
            float mNewR = bperm_f(aP1, mNew);
            float ax = fabsf(gx), ay = fabsf(gy);
            int dNew = (ay <= 0.4142135623730951f * ax) ? 0
                     : (ay >= 2.414213562373095f * ax) ? 2
                     : (((gx > 0.f) == (gy > 0.f)) ? 1 : 3);
            mPrev = mCur; mPrevL = mCurL; mPrevR = mCurR;
            mCur = mNew; mCurL = mNewL; mCurR = mNewR;
            dCur = dNew;
        }
    }

    // ---- steady: i = 8..RB+7, one output row each ----
#pragma unroll
    for (int ii = 0; ii < RB; ii++) {
        const int i = 8 + ii;
        float g = 0.299f * rN + 0.587f * gN + 0.114f * bN;
        {   // prefetch next row (last one reads a reflected valid row)
            int gr = reflect_idx(y0 - 3 + i, H);
            const float* p = src + (size_t)gr * W + cx;
            rN = p[0]; gN = p[IMG]; bN = p[2 * IMG];
        }
        float gm1 = bperm_f(aM1, g), gp1 = bperm_f(aP1, g);
        float gm2 = bperm_f(aM2, g), gp2 = bperm_f(aP2, g);
        float gm3 = bperm_f(aM3, g), gp3 = bperm_f(aP3, g);
#pragma unroll
        for (int j = 0; j < 6; j++) { hx[j] = hx[j + 1]; hy[j] = hy[j + 1]; }
        hx[6] = A3 * (gp1 - gm1) + A2 * (gp2 - gm2) + A1 * (gp3 - gm3);
        hy[6] = S3 * g + S2 * (gp1 + gm1) + S1 * (gp2 + gm2) + S0 * (gp3 + gm3);

        float gx = S3 * hx[3] + S2 * (hx[4] + hx[2])
                 + S1 * (hx[5] + hx[1]) + S0 * (hx[6] + hx[0]);
        float gy = A3 * (hy[4] - hy[2]) + A2 * (hy[5] - hy[1])
                 + A1 * (hy[6] - hy[0]);
        int mr = y0 - 7 + i;
        bool ok = colok && ((unsigned)mr < (unsigned)H);
        float mNew = ok ? (gx * gx + gy * gy + 1e-12f) : 0.f;      // mag^2
        float mNewL = bperm_f(aM1, mNew);
        float mNewR = bperm_f(aP1, mNew);
        float ax = fabsf(gx), ay = fabsf(gy);
        int dNew = (ay <= 0.4142135623730951f * ax) ? 0
                 : (ay >= 2.414213562373095f * ax) ? 2
                 : (((gx > 0.f) == (gy > 0.f)) ? 1 : 3);

        // NMS + thresholds at row t = y0 + ii
        float n1 = (dCur == 0) ? mCurR : (dCur == 1) ? mNewR
                 : (dCur == 2) ? mNew : mNewL;
        float n2 = (dCur == 0) ? mCurL : (dCur == 1) ? mPrevL
                 : (dCur == 2) ? mPrev : mPrevR;
        bool okn = (mCur >= n1) && (mCur >= n2);
        u64 bs = __ballot(okn && (mCur >= 0.04f));   // (0.2)^2
        u64 bw = __ballot(okn && (mCur >= 0.01f));   // (0.1)^2
        int t = y0 + ii;
        if (lane == 0 && t < H) {
            strongP[outBase + t] = (bs >> 4) & omask;
            weakP[outBase + t] = (bw >> 4) & omask;
        }

        mPrev = mCur; mPrevL = mCurL; mPrevR = mCurR;
        mCur = mNew; mCurL = mNewL; mCurR = mNewR;
        dCur = dNew;
    }
}

// ---------------------------------------------------------------------------
// Kernel 2: bit-parallel hysteresis (10 iters, exact via light cone) + diff
// count. One wave per 32x32 tile per image-pair; lane l = row ty0-10+l.
// Loads from 56-bit strip words via 3-word funnel shift.
// ---------------------------------------------------------------------------
__device__ __forceinline__ u64 ldw10(const u64* p, int img, int y, int q, bool ok) {
    return (ok && q >= 0 && q < NSTRIP) ? p[((size_t)img * NSTRIP + q) * H + y] : 0ULL;
}

__global__ __launch_bounds__(256) void k_hyst(const u64* __restrict__ strongP,
                                              const u64* __restrict__ weakP,
                                              unsigned int* __restrict__ partials) {
    __shared__ unsigned int part[4];
    const int wy = threadIdx.x >> 6;
    const int wave = blockIdx.x * 4 + wy;
    const int lane = threadIdx.x & 63;
    const int tile = wave & 255;
    const int pair = wave >> 8;          // 0..15
    const int tx0 = (tile & 15) * 32;
    const int ty0 = (tile >> 4) * 32;

    const int y = ty0 - 10 + lane;
    const bool rowok = (lane < 52) && (y >= 0) && (y < H);
    const int yc = rowok ? y : 0;

    // window covers cols x .. x+63; 56-bit words
    const int x = tx0 - 10;
    const int q0 = (x < 0) ? -1 : (x / 56);
    const int r = x - 56 * q0;           // 1..55, never 0 for our x values
    const int sh1 = 56 - r;
    const bool need3 = (r > 48);
    const int sh2 = 112 - r;             // < 64 iff need3

    const int imgA = pair, imgB = pair + 16;
    u64 sA, wA, sB, wB;
    {
        u64 w0, w1, w2;
        w0 = ldw10(strongP, imgA, yc, q0, rowok);
        w1 = ldw10(strongP, imgA, yc, q0 + 1, rowok);
        w2 = need3 ? ldw10(strongP, imgA, yc, q0 + 2, rowok) : 0ULL;
        sA = (w0 >> r) | (w1 << sh1) | (need3 ? (w2 << sh2) : 0ULL);
        w0 = ldw10(weakP, imgA, yc, q0, rowok);
        w1 = ldw10(weakP, imgA, yc, q0 + 1, rowok);
        w2 = need3 ? ldw10(weakP, imgA, yc, q0 + 2, rowok) : 0ULL;
        wA = (w0 >> r) | (w1 << sh1) | (need3 ? (w2 << sh2) : 0ULL);
        w0 = ldw10(strongP, imgB, yc, q0, rowok);
        w1 = ldw10(strongP, imgB, yc, q0 + 1, rowok);
        w2 = need3 ? ldw10(strongP, imgB, yc, q0 + 2, rowok) : 0ULL;
        sB = (w0 >> r) | (w1 << sh1) | (need3 ? (w2 << sh2) : 0ULL);
        w0 = ldw10(weakP, imgB, yc, q0, rowok);
        w1 = ldw10(weakP, imgB, yc, q0 + 1, rowok);
        w2 = need3 ? ldw10(weakP, imgB, yc, q0 + 2, rowok) : 0ULL;
        wB = (w0 >> r) | (w1 << sh1) | (need3 ? (w2 << sh2) : 0ULL);
    }

#pragma unroll
    for (int it = 0; it < 10; it++) {
        u64 up = __shfl_up(sA, 1), dn = __shfl_down(sA, 1);
        u64 t = up | sA | dn;
        sA |= (t | (t << 1) | (t >> 1)) & wA;
        up = __shfl_up(sB, 1); dn = __shfl_down(sB, 1);
        t = up | sB | dn;
        sB |= (t | (t << 1) | (t >> 1)) & wB;
    }

    // central 32x32: lanes 10..41, bits 10..41
    unsigned int cgt = 0;
    if (lane >= 10 && lane < 42) {
        const u64 mask = ((1ULL << 42) - (1ULL << 10));
        cgt = (unsigned int)__popcll((sA ^ sB) & mask);
    }
#pragma unroll
    for (int off = 32; off > 0; off >>= 1) cgt += __shfl_down(cgt, off);
    if (lane == 0) part[wy] = cgt;
    __syncthreads();
    if (threadIdx.x == 0)
        partials[blockIdx.x] = part[0] + part[1] + part[2] + part[3];
}

// ---------------------------------------------------------------------------
// Kernel 3: sum 1024 partials, scale, write scalar. One block.
// ---------------------------------------------------------------------------
__global__ __launch_bounds__(256) void k_final(const unsigned int* __restrict__ partials,
                                               float* __restrict__ out) {
    __shared__ unsigned int part[4];
    unsigned int c = 0;
    for (int i = threadIdx.x; i < 1024; i += 256) c += partials[i];
#pragma unroll
    for (int off = 32; off > 0; off >>= 1) c += __shfl_down(c, off);
    const int lane = threadIdx.x & 63;
    const int wy = threadIdx.x >> 6;
    if (lane == 0) part[wy] = c;
    __syncthreads();
    if (threadIdx.x == 0)
        out[0] = (float)(part[0] + part[1] + part[2] + part[3]) * (1.0f / 4194304.0f);
}

extern "C" void kernel_launch(void* const* d_in, const int* in_sizes, int n_in,
                              void* d_out, int out_size, void* d_ws, size_t ws_size,
                              hipStream_t stream) {
    const float* yhat = (const float*)d_in[0];
    const float* yy = (const float*)d_in[1];

    u64* strongP = (u64*)d_ws;                        // 32*10*512 u64 = 1.31 MB
    u64* weakP = strongP + (size_t)NIMG * NSTRIP * H; // 1.31 MB
    unsigned int* partials = (unsigned int*)(weakP + (size_t)NIMG * NSTRIP * H);

    // 32 img x 10 strips x 20 bands = 6400 waves, 4 waves/block
    k_edges<<<1600, 256, 0, stream>>>(yhat, yy, strongP, weakP);

    // 256 tiles x 16 pairs = 4096 waves, 4 waves/block
    k_hyst<<<1024, 256, 0, stream>>>(strongP, weakP, partials);
    k_final<<<1, 256, 0, stream>>>(partials, (float*)d_out);
}

// Round 10
// 135.571 us; speedup vs baseline: 1.1348x; 1.0520x over previous
//
#include <hip/hip_runtime.h>
#include <math.h>

#define H 512
#define W 512
#define IMG (H*W)
#define NIMG 32           // 16 images from y_hat + 16 from y
#define NSTRIP 10         // 56-col output strips per row
#define SW 56
#define RB 32             // output rows per band
#define NBAND 16          // 16*32 = 512 exactly

typedef unsigned long long u64;

__device__ __forceinline__ int reflect_idx(int i, int n) {
    if (i < 0) i = -i;
    if (i >= n) i = 2 * n - 2 - i;
    return i;
}

__device__ __forceinline__ float bperm_f(int addr, float v) {
    return __int_as_float(__builtin_amdgcn_ds_bpermute(addr, __float_as_int(v)));
}

// Composed 7-tap kernels: blur(5-tap gaussian) composed with sobel [1,2,1]/[-1,0,1].
#define S0 0.05448868454964294f
#define S1 0.35317871110251920f
#define S2 0.94551131545035710f
#define S3 1.29364257779496160f
#define A1 0.05448868454964294f
#define A2 0.24420134200323332f
#define A3 0.34813126234460456f

// ---------------------------------------------------------------------------
// Kernel 1 (line-scan, row-PAIR pipelined): one wave per (image,strip,band).
// Lane = gray col 56s-4+lane. Each iteration: consume 2 prefetched rows,
// prefetch next 2 (6 loads in flight across the whole iteration body),
// 2 h-rows via 12 bpermutes, 2 mag rows, 2 NMS rows, one 16B paired store.
// Output: 56-bit words, plane[img][strip][row].
// ---------------------------------------------------------------------------
__global__ __launch_bounds__(256, 5) void k_edges(const float* __restrict__ yhat,
                                                  const float* __restrict__ yy,
                                                  u64* __restrict__ strongP,
                                                  u64* __restrict__ weakP) {
    const int wid = blockIdx.x * 4 + (threadIdx.x >> 6);
    const int lane = threadIdx.x & 63;
    const int n = wid / (NSTRIP * NBAND);
    const int rem = wid - n * (NSTRIP * NBAND);
    const int s = rem / NBAND;
    const int band = rem - s * NBAND;
    const int y0 = band * RB;
    const float* src = (n < 16) ? (yhat + (size_t)n * 3 * IMG)
                                : (yy + (size_t)(n - 16) * 3 * IMG);

    const int c = s * SW - 4 + lane;
    const int cx = reflect_idx(c, W);
    const bool colok = ((unsigned)c < (unsigned)W);
    const u64 omask = (s == 9) ? 0xFFull : 0x00FFFFFFFFFFFFFFull;

    const int aM3 = ((lane - 3) << 2), aM2 = ((lane - 2) << 2), aM1 = ((lane - 1) << 2);
    const int aP1 = ((lane + 1) << 2), aP2 = ((lane + 2) << 2), aP3 = ((lane + 3) << 2);

    float hx[7], hy[7];
#pragma unroll
    for (int j = 0; j < 7; j++) { hx[j] = 0.f; hy[j] = 0.f; }

    const u64 outBase = ((size_t)n * NSTRIP + s) * H;

    // prefetched pair registers
    float r0, g0c, b0, r1, g1c, b1;
    {
        const float* p0 = src + (size_t)reflect_idx(y0 - 4, H) * W + cx;
        const float* p1 = src + (size_t)reflect_idx(y0 - 3, H) * W + cx;
        r0 = p0[0]; g0c = p0[IMG]; b0 = p0[2 * IMG];
        r1 = p1[0]; g1c = p1[IMG]; b1 = p1[2 * IMG];
    }

#define PREFETCH(k)                                                             \
    {                                                                           \
        const float* p0 = src + (size_t)reflect_idx(y0 - 4 + 2 * (k), H) * W + cx; \
        const float* p1 = src + (size_t)reflect_idx(y0 - 3 + 2 * (k), H) * W + cx; \
        r0 = p0[0]; g0c = p0[IMG]; b0 = p0[2 * IMG];                            \
        r1 = p1[0]; g1c = p1[IMG]; b1 = p1[2 * IMG];                            \
    }

#define HPUSH(gv)                                                               \
    {                                                                           \
        float gm1 = bperm_f(aM1, gv), gp1 = bperm_f(aP1, gv);                   \
        float gm2 = bperm_f(aM2, gv), gp2 = bperm_f(aP2, gv);                   \
        float gm3 = bperm_f(aM3, gv), gp3 = bperm_f(aP3, gv);                   \
        _Pragma("unroll")                                                       \
        for (int j = 0; j < 6; j++) { hx[j] = hx[j + 1]; hy[j] = hy[j + 1]; }   \
        hx[6] = A3 * (gp1 - gm1) + A2 * (gp2 - gm2) + A1 * (gp3 - gm3);         \
        hy[6] = S3 * gv + S2 * (gp1 + gm1) + S1 * (gp2 + gm2) + S0 * (gp3 + gm3); \
    }

    // MAG computes mag^2 + L/R + dir for FIFO-center row `mr`
#define MAG(mr, mv, mvL, mvR, dv)                                               \
    {                                                                           \
        float gx = S3 * hx[3] + S2 * (hx[4] + hx[2])                            \
                 + S1 * (hx[5] + hx[1]) + S0 * (hx[6] + hx[0]);                 \
        float gy = A3 * (hy[4] - hy[2]) + A2 * (hy[5] - hy[1])                  \
                 + A1 * (hy[6] - hy[0]);                                        \
        bool okm = colok && ((unsigned)(mr) < (unsigned)H);                     \
        mv = okm ? (gx * gx + gy * gy + 1e-12f) : 0.f;                          \
        mvL = bperm_f(aM1, mv);                                                 \
        mvR = bperm_f(aP1, mv);                                                 \
        float ax = fabsf(gx), ay = fabsf(gy);                                   \
        dv = (ay <= 0.4142135623730951f * ax) ? 0                               \
           : (ay >= 2.414213562373095f * ax) ? 2                                \
           : (((gx > 0.f) == (gy > 0.f)) ? 1 : 3);                              \
    }

    // ---- prime: pairs 0..2 fill FIFO (gray rows 0..5) ----
#pragma unroll
    for (int k = 0; k < 3; k++) {
        float ga = 0.299f * r0 + 0.587f * g0c + 0.114f * b0;
        float gb = 0.299f * r1 + 0.587f * g1c + 0.114f * b1;
        PREFETCH(k + 1);
        HPUSH(ga);
        HPUSH(gb);
    }

    // pair 3: gray rows 6,7 -> mag rows y0-1, y0
    float mm1, mm1L, mm1R, m0, m0L, m0R;
    int dir0;
    {
        float ga = 0.299f * r0 + 0.587f * g0c + 0.114f * b0;
        float gb = 0.299f * r1 + 0.587f * g1c + 0.114f * b1;
        PREFETCH(4);
        int dtmp;
        HPUSH(ga);
        MAG(y0 - 1, mm1, mm1L, mm1R, dtmp);
        (void)dtmp;
        HPUSH(gb);
        MAG(y0, m0, m0L, m0R, dir0);
    }

    // ---- steady: pairs k=4..19; outputs rows t0=y0+2k-8, t1=t0+1 ----
#pragma unroll 4
    for (int k = 4; k < 20; k++) {
        float ga = 0.299f * r0 + 0.587f * g0c + 0.114f * b0;
        float gb = 0.299f * r1 + 0.587f * g1c + 0.114f * b1;
        if (k < 19) PREFETCH(k + 1);

        float ma, maL, maR, mb, mbL, mbR;
        int da, db;
        HPUSH(ga);
        MAG(y0 + 2 * k - 7, ma, maL, maR, da);
        HPUSH(gb);
        MAG(y0 + 2 * k - 6, mb, mbL, mbR, db);

        // row t0: mags (mm1, m0, ma), dir0
        float n1 = (dir0 == 0) ? m0R : (dir0 == 1) ? maR : (dir0 == 2) ? ma : maL;
        float n2 = (dir0 == 0) ? m0L : (dir0 == 1) ? mm1L : (dir0 == 2) ? mm1 : mm1R;
        bool ok0 = (m0 >= n1) && (m0 >= n2);
        u64 bs0 = __ballot(ok0 && (m0 >= 0.04f));
        u64 bw0 = __ballot(ok0 && (m0 >= 0.01f));

        // row t1: mags (m0, ma, mb), dir = da
        float n3 = (da == 0) ? maR : (da == 1) ? mbR : (da == 2) ? mb : mbL;
        float n4 = (da == 0) ? maL : (da == 1) ? m0L : (da == 2) ? m0 : m0R;
        bool ok1 = (ma >= n3) && (ma >= n4);
        u64 bs1 = __ballot(ok1 && (ma >= 0.04f));
        u64 bw1 = __ballot(ok1 && (ma >= 0.01f));

        if (lane == 0) {
            int t0 = y0 + 2 * k - 8;
            ulonglong2 vs, vw;
            vs.x = (bs0 >> 4) & omask; vs.y = (bs1 >> 4) & omask;
            vw.x = (bw0 >> 4) & omask; vw.y = (bw1 >> 4) & omask;
            *(ulonglong2*)&strongP[outBase + t0] = vs;
            *(ulonglong2*)&weakP[outBase + t0] = vw;
        }

        mm1 = ma; mm1L = maL; mm1R = maR;
        m0 = mb; m0L = mbL; m0R = mbR;
        dir0 = db;
    }
#undef PREFETCH
#undef HPUSH
#undef MAG
}

// ---------------------------------------------------------------------------
// Kernel 2: bit-parallel hysteresis (10 iters, exact via light cone) + diff
// count. One wave per 32x32 tile per image-pair; lane l = row ty0-10+l.
// Loads from 56-bit strip words via 3-word funnel shift.
// ---------------------------------------------------------------------------
__device__ __forceinline__ u64 ldw10(const u64* p, int img, int y, int q, bool ok) {
    return (ok && q >= 0 && q < NSTRIP) ? p[((size_t)img * NSTRIP + q) * H + y] : 0ULL;
}

__global__ __launch_bounds__(256) void k_hyst(const u64* __restrict__ strongP,
                                              const u64* __restrict__ weakP,
                                              unsigned int* __restrict__ partials) {
    __shared__ unsigned int part[4];
    const int wy = threadIdx.x >> 6;
    const int wave = blockIdx.x * 4 + wy;
    const int lane = threadIdx.x & 63;
    const int tile = wave & 255;
    const int pair = wave >> 8;          // 0..15
    const int tx0 = (tile & 15) * 32;
    const int ty0 = (tile >> 4) * 32;

    const int y = ty0 - 10 + lane;
    const bool rowok = (lane < 52) && (y >= 0) && (y < H);
    const int yc = rowok ? y : 0;

    const int x = tx0 - 10;
    const int q0 = (x < 0) ? -1 : (x / 56);
    const int r = x - 56 * q0;           // 1..55, never 0
    const int sh1 = 56 - r;
    const bool need3 = (r > 48);
    const int sh2 = 112 - r;

    const int imgA = pair, imgB = pair + 16;
    u64 sA, wA, sB, wB;
    {
        u64 w0, w1, w2;
        w0 = ldw10(strongP, imgA, yc, q0, rowok);
        w1 = ldw10(strongP, imgA, yc, q0 + 1, rowok);
        w2 = need3 ? ldw10(strongP, imgA, yc, q0 + 2, rowok) : 0ULL;
        sA = (w0 >> r) | (w1 << sh1) | (need3 ? (w2 << sh2) : 0ULL);
        w0 = ldw10(weakP, imgA, yc, q0, rowok);
        w1 = ldw10(weakP, imgA, yc, q0 + 1, rowok);
        w2 = need3 ? ldw10(weakP, imgA, yc, q0 + 2, rowok) : 0ULL;
        wA = (w0 >> r) | (w1 << sh1) | (need3 ? (w2 << sh2) : 0ULL);
        w0 = ldw10(strongP, imgB, yc, q0, rowok);
        w1 = ldw10(strongP, imgB, yc, q0 + 1, rowok);
        w2 = need3 ? ldw10(strongP, imgB, yc, q0 + 2, rowok) : 0ULL;
        sB = (w0 >> r) | (w1 << sh1) | (need3 ? (w2 << sh2) : 0ULL);
        w0 = ldw10(weakP, imgB, yc, q0, rowok);
        w1 = ldw10(weakP, imgB, yc, q0 + 1, rowok);
        w2 = need3 ? ldw10(weakP, imgB, yc, q0 + 2, rowok) : 0ULL;
        wB = (w0 >> r) | (w1 << sh1) | (need3 ? (w2 << sh2) : 0ULL);
    }

#pragma unroll
    for (int it = 0; it < 10; it++) {
        u64 up = __shfl_up(sA, 1), dn = __shfl_down(sA, 1);
        u64 t = up | sA | dn;
        sA |= (t | (t << 1) | (t >> 1)) & wA;
        up = __shfl_up(sB, 1); dn = __shfl_down(sB, 1);
        t = up | sB | dn;
        sB |= (t | (t << 1) | (t >> 1)) & wB;
    }

    unsigned int cgt = 0;
    if (lane >= 10 && lane < 42) {
        const u64 mask = ((1ULL << 42) - (1ULL << 10));
        cgt = (unsigned int)__popcll((sA ^ sB) & mask);
    }
#pragma unroll
    for (int off = 32; off > 0; off >>= 1) cgt += __shfl_down(cgt, off);
    if (lane == 0) part[wy] = cgt;
    __syncthreads();
    if (threadIdx.x == 0)
        partials[blockIdx.x] = part[0] + part[1] + part[2] + part[3];
}

// ---------------------------------------------------------------------------
// Kernel 3: sum 1024 partials, scale, write scalar. One block.
// ---------------------------------------------------------------------------
__global__ __launch_bounds__(256) void k_final(const unsigned int* __restrict__ partials,
                                               float* __restrict__ out) {
    __shared__ unsigned int part[4];
    unsigned int c = 0;
    for (int i = threadIdx.x; i < 1024; i += 256) c += partials[i];
#pragma unroll
    for (int off = 32; off > 0; off >>= 1) c += __shfl_down(c, off);
    const int lane = threadIdx.x & 63;
    const int wy = threadIdx.x >> 6;
    if (lane == 0) part[wy] = c;
    __syncthreads();
    if (threadIdx.x == 0)
        out[0] = (float)(part[0] + part[1] + part[2] + part[3]) * (1.0f / 4194304.0f);
}

extern "C" void kernel_launch(void* const* d_in, const int* in_sizes, int n_in,
                              void* d_out, int out_size, void* d_ws, size_t ws_size,
                              hipStream_t stream) {
    const float* yhat = (const float*)d_in[0];
    const float* yy = (const float*)d_in[1];

    u64* strongP = (u64*)d_ws;                        // 32*10*512 u64 = 1.31 MB
    u64* weakP = strongP + (size_t)NIMG * NSTRIP * H; // 1.31 MB
    unsigned int* partials = (unsigned int*)(weakP + (size_t)NIMG * NSTRIP * H);

    // 32 img x 10 strips x 16 bands = 5120 waves, 4 waves/block
    k_edges<<<1280, 256, 0, stream>>>(yhat, yy, strongP, weakP);

    // 256 tiles x 16 pairs = 4096 waves, 4 waves/block
    k_hyst<<<1024, 256, 0, stream>>>(strongP, weakP, partials);
    k_final<<<1, 256, 0, stream>>>(partials, (float*)d_out);
}